// Round 17
// baseline (132.592 us; speedup 1.0000x reference)
//
#include <hip/hip_runtime.h>
#include <stdint.h>

constexpr int T_TOK = 8192;
constexpr int D_DIM = 1024;
constexpr int H_DIM = 2048;
constexpr int E_NUM = 8;

typedef __bf16 bf16x8 __attribute__((ext_vector_type(8)));
typedef float  f32x4  __attribute__((ext_vector_type(4)));

static __device__ __forceinline__ unsigned short f2bf(float f) {
  union { float f; unsigned u; } a; a.f = f;
  unsigned r = a.u + 0x7fffu + ((a.u >> 16) & 1u);   // RNE
  return (unsigned short)(r >> 16);
}

// ---------------- fp32 -> bf16 conversion (x only) ----------------
__global__ void cvt_f32_bf16(const float* __restrict__ src,
                             unsigned short* __restrict__ dst, int n4) {
  int i = blockIdx.x * blockDim.x + threadIdx.x;
  int stride = gridDim.x * blockDim.x;
  for (; i < n4; i += stride) {
    float4 v = reinterpret_cast<const float4*>(src)[i];
    ushort4 o;
    o.x = f2bf(v.x); o.y = f2bf(v.y); o.z = f2bf(v.z); o.w = f2bf(v.w);
    reinterpret_cast<ushort4*>(dst)[i] = o;
  }
}

#define FENCE() asm volatile("" ::: "memory")
#define BARRIER() do { FENCE(); __builtin_amdgcn_s_barrier(); FENCE(); } while (0)
#define WAIT_LGKM0() asm volatile("s_waitcnt lgkmcnt(0)" ::: "memory")
#define WAIT_VM(N) asm volatile("s_waitcnt vmcnt(%0)" :: "i"(N) : "memory")

// ==== 128x128 grouped GEMM, m97-structure (2-barrier-equiv, 3 blocks/CU) ====
// A bf16 (T,K) via global_load_lds; B fp32 (E,N,K) via global_load_lds with
// fp32->bf16 convert on the LDS-READ side (r15-proven mechanism + swizzles).
// 256 threads = 4 waves (2x2); per-wave output 64x64; 16 MFMA per K-step.
// LDS 48 KiB -> 3 blocks/CU: cross-block wave overlap absorbs barrier drain
// (m114/m103 regime). One barrier + one WAIT_VM(0) per K-step:
//   iter top: vm(0) drains own stages (issued last iter, ~full body cover);
//   BARRIER: all stages complete AND all prior reads complete (reads drain
//   via lgkm0 before MFMA before loop-back) -> staging buf^1 is safe.
template <int K_DIM, int N_DIM, bool RELU2>
__global__ __launch_bounds__(256, 4)
void gg128(const unsigned short* __restrict__ A,
           const float* __restrict__ Bw,
           const int* __restrict__ counts,
           void* __restrict__ Cout) {
  constexpr int BM = 128, BK = 32, BN = 128;
  constexpr int NT = K_DIM / BK;
  constexpr int NCOLT = N_DIM / BN;     // 16 (G1) / 8 (G2)

  const int tid  = threadIdx.x;
  const int wid  = tid >> 6;
  const int lane = tid & 63;
  const int wr   = wid >> 1;            // 0..1
  const int wc   = wid & 1;             // 0..1

  // ---- XCD swizzle: hardware XCD = linear id % 8; pin col-tiles per XCD
  const int id = blockIdx.x + gridDim.x * blockIdx.y;
  int ct, rt;
  if constexpr (NCOLT == 16) { ct = (id & 7) | (((id >> 3) & 1) << 3); rt = id >> 4; }
  else                       { ct = id & 7;                            rt = id >> 3; }

  // ---- rt -> (expert, 128-row tile)
  int t = rt;
  int e = -1, rowBase = 0, rowsValid = 0;
  {
    int tiles = 0, off = 0;
#pragma unroll
    for (int i = 0; i < E_NUM; ++i) {
      int n  = counts[i];
      int nt = (n + BM - 1) / BM;
      if (e < 0 && t < tiles + nt) {
        e = i;
        int lt = t - tiles;
        rowBase   = off + lt * BM;
        rowsValid = n - lt * BM;
        if (rowsValid > BM) rowsValid = BM;
      }
      tiles += nt; off += n;
    }
  }
  if (e < 0) return;
  const int colBase = ct * BN;

  // LDS: A bf16 dbuf 2x8K + B fp32 dbuf 2x16K = 48 KiB -> 3 blocks/CU
  __shared__ __align__(1024) char lds[2 * (BM * 64) + 2 * (BN * 128)];
  auto ldsA = [&](int b) -> char* { return lds + b * (BM * 64); };
  auto ldsB = [&](int b) -> char* { return lds + 2 * (BM * 64) + b * (BN * 128); };

  const char* gA = (const char*)A + (size_t)rowBase * (K_DIM * 2);
  const char* gB = (const char*)Bw + ((size_t)e * N_DIM + colBase) * (size_t)(K_DIM * 4);

  // stage A K-step slab (128 rows x 64B bf16): 2 issues/wave
  auto stageA = [&](int buf, int kt) {
#pragma unroll
    for (int j = 0; j < 2; ++j) {
      int row0u = j * 64 + wid * 16;               // wave-uniform
      int r  = row0u + (lane >> 2);
      int sr = (r < rowsValid) ? r : rowsValid - 1;
      int sg = (lane & 3) ^ ((r >> 1) & 3);        // inverse source swizzle
      const char* src = gA + (size_t)sr * (K_DIM * 2) + (size_t)kt * 64 + sg * 16;
      __builtin_amdgcn_global_load_lds(
          (const __attribute__((address_space(1))) void*)src,
          (__attribute__((address_space(3))) void*)(ldsA(buf) + row0u * 64),
          16, 0, 0);
    }
  };
  // stage B K-step slab (128 rows x 128B fp32): 4 issues/wave
  auto stageB = [&](int buf, int kt) {
#pragma unroll
    for (int j = 0; j < 4; ++j) {
      int row0u = j * 32 + wid * 8;
      int r  = row0u + (lane >> 3);
      int sg = (lane & 7) ^ (r & 7);
      const char* src = gB + (size_t)r * (K_DIM * 4) + (size_t)kt * 128 + sg * 16;
      __builtin_amdgcn_global_load_lds(
          (const __attribute__((address_space(1))) void*)src,
          (__attribute__((address_space(3))) void*)(ldsB(buf) + row0u * 128),
          16, 0, 0);
    }
  };

  const int rl = lane & 15;
  const int gh = lane >> 4;             // 0..3

  bf16x8 aF[4], bF[4];
  f32x4  accC[4][4];
#pragma unroll
  for (int m = 0; m < 4; ++m)
#pragma unroll
    for (int n = 0; n < 4; ++n) accC[m][n] = (f32x4){0.f, 0.f, 0.f, 0.f};

  auto readA = [&](int buf) {
    const char* base = ldsA(buf);
#pragma unroll
    for (int m = 0; m < 4; ++m) {
      int r = wr * 64 + m * 16 + rl;
      int g = gh ^ ((r >> 1) & 3);
      aF[m] = *(const bf16x8*)(base + r * 64 + g * 16);
    }
  };
  auto readB = [&](int buf) {
    const char* base = ldsB(buf);
#pragma unroll
    for (int n = 0; n < 4; ++n) {
      int r = wc * 64 + n * 16 + rl;
      const char* rb = base + r * 128;
      f32x4 v0 = *(const f32x4*)(rb + (((2 * gh + 0) ^ (r & 7)) * 16));
      f32x4 v1 = *(const f32x4*)(rb + (((2 * gh + 1) ^ (r & 7)) * 16));
      union { __bf16 b[8]; bf16x8 v; } u;
#pragma unroll
      for (int p = 0; p < 4; ++p) {
        u.b[p]     = (__bf16)v0[p];                // v_cvt_pk_bf16_f32
        u.b[4 + p] = (__bf16)v1[p];
      }
      bF[n] = u.v;
    }
  };

  // ---- prologue: stage step 0
  stageA(0, 0); stageB(0, 0);

  for (int t2 = 0; t2 < NT; ++t2) {
    WAIT_VM(0);                          // own stages (prev iter) complete
    BARRIER();                           // publish buf[t2&1]; prior reads done
    const int ks = (t2 + 1 < NT) ? t2 + 1 : NT - 1;   // tail re-stage benign
    const int bn = (t2 + 1) & 1, bc = t2 & 1;
    stageA(bn, ks);                      // into non-read buffer
    stageB(bn, ks);
    readA(bc);
    readB(bc);
    WAIT_LGKM0();
    __builtin_amdgcn_s_setprio(1);
#pragma unroll
    for (int m = 0; m < 4; ++m)
#pragma unroll
      for (int n = 0; n < 4; ++n)
        accC[m][n] = __builtin_amdgcn_mfma_f32_16x16x32_bf16(
            aF[m], bF[n], accC[m][n], 0, 0, 0);
    __builtin_amdgcn_s_setprio(0);
  }
  WAIT_VM(0);                            // drain tail stages (LDS-dest only)

  // ---- epilogue. C/D: col = lane&15, row = (lane>>4)*4 + j
  const int rB0 = wr * 64 + gh * 4;
  const int cB0 = colBase + wc * 64 + rl;
#pragma unroll
  for (int m = 0; m < 4; ++m) {
#pragma unroll
    for (int n = 0; n < 4; ++n) {
#pragma unroll
      for (int j = 0; j < 4; ++j) {
        int r = rB0 + m * 16 + j;
        if (r < rowsValid) {
          size_t idx = (size_t)(rowBase + r) * N_DIM + (cB0 + n * 16);
          float v = accC[m][n][j];
          if (RELU2) {
            float rv = v > 0.f ? v : 0.f;
            float hf = (float)(__bf16)rv;              // bf16(relu(acc))
            ((__bf16*)Cout)[idx] = (__bf16)(hf * hf);  // bf16 square
          } else {
            ((float*)Cout)[idx] = (float)(__bf16)v;    // float(bf16(acc))
          }
        }
      }
    }
  }
}

extern "C" void kernel_launch(void* const* d_in, const int* in_sizes, int n_in,
                              void* d_out, int out_size, void* d_ws, size_t ws_size,
                              hipStream_t stream) {
  const float* x   = (const float*)d_in[0];
  const int*   cnt = (const int*)d_in[1];
  const float* wu  = (const float*)d_in[2];
  const float* wd  = (const float*)d_in[3];
  float* out = (float*)d_out;
  char*  ws  = (char*)d_ws;

  unsigned short* xb   = (unsigned short*)(ws);                // 16 MiB
  unsigned short* hbuf = (unsigned short*)(ws + (16u << 20));  // 32 MiB

  cvt_f32_bf16<<<2048, 256, 0, stream>>>(x, xb, T_TOK * D_DIM / 4);

  // grid.x = max row tiles: floor(T/128) + E = 72 (excess blocks exit early)
  // GEMM1: h = bf16(bf16(relu(x@wu^T))^2); grid 72x16
  gg128<D_DIM, H_DIM, true ><<<dim3(72, H_DIM / 128), dim3(256), 0, stream>>>(
      xb, wu, cnt, (void*)hbuf);
  // GEMM2: out = float(bf16(h@wd^T)); grid 72x8
  gg128<H_DIM, D_DIM, false><<<dim3(72, D_DIM / 128), dim3(256), 0, stream>>>(
      hbuf, wd, cnt, (void*)out);
}

// Round 18
// 112.236 us; speedup vs baseline: 1.1814x; 1.1814x over previous
//
#include <hip/hip_runtime.h>
#include <stdint.h>

constexpr int T_TOK = 8192;
constexpr int D_DIM = 1024;
constexpr int H_DIM = 2048;
constexpr int E_NUM = 8;

typedef __bf16 bf16x8 __attribute__((ext_vector_type(8)));
typedef float  f32x4  __attribute__((ext_vector_type(4)));

static __device__ __forceinline__ unsigned short f2bf(float f) {
  union { float f; unsigned u; } a; a.f = f;
  unsigned r = a.u + 0x7fffu + ((a.u >> 16) & 1u);   // RNE
  return (unsigned short)(r >> 16);
}

// ---------------- fp32 -> bf16 conversion (x only) ----------------
__global__ void cvt_f32_bf16(const float* __restrict__ src,
                             unsigned short* __restrict__ dst, int n4) {
  int i = blockIdx.x * blockDim.x + threadIdx.x;
  int stride = gridDim.x * blockDim.x;
  for (; i < n4; i += stride) {
    float4 v = reinterpret_cast<const float4*>(src)[i];
    ushort4 o;
    o.x = f2bf(v.x); o.y = f2bf(v.y); o.z = f2bf(v.z); o.w = f2bf(v.w);
    reinterpret_cast<ushort4*>(dst)[i] = o;
  }
}

#define FENCE() asm volatile("" ::: "memory")
#define BARRIER() do { FENCE(); __builtin_amdgcn_s_barrier(); FENCE(); } while (0)
#define WAIT_LGKM0() asm volatile("s_waitcnt lgkmcnt(0)" ::: "memory")
#define WAIT_VM(N) asm volatile("s_waitcnt vmcnt(%0)" :: "i"(N) : "memory")

// ==== multi-buffered BK=32 grouped GEMM; all staging via global_load_lds ====
// A: (T,K) bf16. B: (E,N,K) fp32, converted to bf16 on the LDS-READ side.
// One barrier + one counted WAIT_VM per K-step; stages issued D = BUFS-1
// steps ahead. Ledger: entering step t, outstanding = D batches of ISS;
// WAIT_VM((D-1)*ISS) drains step t's batch; BARRIER publishes buf[t%BUFS];
// body stages step t+D into buf[(t+D)%BUFS], whose previous reader (step
// t+D-BUFS = t-1) completed its ds_reads (lgkm0 -> MFMA) before this
// barrier -> cross-wave safe.
// Swizzles (rule #21 both-sides): A 4-granule g^=(r>>1)&3; B 8-granule g^=r&7.
template <int K_DIM, int N_DIM, int BN, int BUFS, bool RELU2>
__global__ __launch_bounds__(512, 2)
void ggt(const unsigned short* __restrict__ A,
         const float* __restrict__ Bw,
         const int* __restrict__ counts,
         void* __restrict__ Cout) {
  constexpr int BM = 256, BK = 32;
  constexpr int NT = K_DIM / BK;
  constexpr int WN = BN / 4;
  constexpr int NACC = WN / 16;
  constexpr int BI  = BN / 64;          // B issues/wave/step
  constexpr int ISS = 2 + BI;
  constexpr int D   = BUFS - 1;         // pipeline depth (steps ahead)

  const int tid  = threadIdx.x;
  const int wid  = tid >> 6;
  const int lane = tid & 63;
  const int wr   = wid >> 2;            // 0..1
  const int wc   = wid & 3;             // 0..3

  // ---- XCD swizzle: 8 col-tiles pinned per XCD (hardware XCD = id % 8)
  const int id = blockIdx.x + gridDim.x * blockIdx.y;
  const int ct = id & 7;
  const int rt = id >> 3;

  // ---- rt -> (expert, 256-row tile)
  int t = rt;
  int e = -1, rowBase = 0, rowsValid = 0;
  {
    int tiles = 0, off = 0;
#pragma unroll
    for (int i = 0; i < E_NUM; ++i) {
      int n  = counts[i];
      int nt = (n + BM - 1) / BM;
      if (e < 0 && t < tiles + nt) {
        e = i;
        int lt = t - tiles;
        rowBase   = off + lt * BM;
        rowsValid = n - lt * BM;
        if (rowsValid > BM) rowsValid = BM;
      }
      tiles += nt; off += n;
    }
  }
  if (e < 0) return;
  const int colBase = ct * BN;

  // LDS: BUFS x (A 16KB + B BN*128B) -> G1(3,256)=144K, G2(4,128)=128K
  __shared__ __align__(1024) char lds[BUFS * (BM * 64 + BN * 128)];
  auto ldsA = [&](int b) -> char* { return lds + b * (BM * 64); };
  auto ldsB = [&](int b) -> char* { return lds + BUFS * (BM * 64) + b * (BN * 128); };

  const char* gA = (const char*)A + (size_t)rowBase * (K_DIM * 2);
  const char* gB = (const char*)Bw + ((size_t)e * N_DIM + colBase) * (size_t)(K_DIM * 4);

  // stage one A K-step slab (256 rows x 64B): 2 issues/wave
  auto stageA = [&](int buf, int kt) {
#pragma unroll
    for (int j = 0; j < 2; ++j) {
      int row0u = j * 128 + wid * 16;              // wave-uniform
      int r  = row0u + (lane >> 2);
      int sr = (r < rowsValid) ? r : rowsValid - 1;
      int sg = (lane & 3) ^ ((r >> 1) & 3);        // inverse source swizzle
      const char* src = gA + (size_t)sr * (K_DIM * 2) + (size_t)kt * 64 + sg * 16;
      __builtin_amdgcn_global_load_lds(
          (const __attribute__((address_space(1))) void*)src,
          (__attribute__((address_space(3))) void*)(ldsA(buf) + row0u * 64),
          16, 0, 0);
    }
  };
  // stage one B K-step slab (BN rows x 128B fp32): BI issues/wave
  auto stageB = [&](int buf, int kt) {
#pragma unroll
    for (int j = 0; j < BI; ++j) {
      int row0u = j * 64 + wid * 8;
      int r  = row0u + (lane >> 3);
      int sg = (lane & 7) ^ (r & 7);
      const char* src = gB + (size_t)r * (K_DIM * 4) + (size_t)kt * 128 + sg * 16;
      __builtin_amdgcn_global_load_lds(
          (const __attribute__((address_space(1))) void*)src,
          (__attribute__((address_space(3))) void*)(ldsB(buf) + row0u * 128),
          16, 0, 0);
    }
  };

  const int rl = lane & 15;
  const int gh = lane >> 4;             // 0..3

  bf16x8 aF[8], bF[NACC];
  f32x4  accC[8][NACC];
#pragma unroll
  for (int m = 0; m < 8; ++m)
#pragma unroll
    for (int n = 0; n < NACC; ++n) accC[m][n] = (f32x4){0.f, 0.f, 0.f, 0.f};

  auto readA = [&](int buf) {
    const char* base = ldsA(buf);
#pragma unroll
    for (int m = 0; m < 8; ++m) {
      int r = wr * 128 + m * 16 + rl;
      int g = gh ^ ((r >> 1) & 3);
      aF[m] = *(const bf16x8*)(base + r * 64 + g * 16);
    }
  };
  auto readB = [&](int buf) {
    const char* base = ldsB(buf);
#pragma unroll
    for (int n = 0; n < NACC; ++n) {
      int r = wc * WN + n * 16 + rl;
      const char* rb = base + r * 128;
      f32x4 v0 = *(const f32x4*)(rb + (((2 * gh + 0) ^ (r & 7)) * 16));
      f32x4 v1 = *(const f32x4*)(rb + (((2 * gh + 1) ^ (r & 7)) * 16));
      union { __bf16 b[8]; bf16x8 v; } u;
#pragma unroll
      for (int p = 0; p < 4; ++p) {
        u.b[p]     = (__bf16)v0[p];                // v_cvt_pk_bf16_f32
        u.b[4 + p] = (__bf16)v1[p];
      }
      bF[n] = u.v;
    }
  };

  // ---- prologue: stage steps 0..D-1
#pragma unroll
  for (int s = 0; s < D; ++s) {
    int ks0 = (s < NT) ? s : NT - 1;
    stageA(s, ks0); stageB(s, ks0);
  }

  for (int t2 = 0; t2 < NT; ++t2) {
    WAIT_VM((D - 1) * ISS);             // drains step-t2's stages
    BARRIER();                          // publishes buf[t2%BUFS]
    const int ks = (t2 + D < NT) ? t2 + D : NT - 1;
    const int bs = (t2 + D) % BUFS;
    const int bc = t2 % BUFS;
    stageA(bs, ks);
    stageB(bs, ks);
    readA(bc);
    readB(bc);
    WAIT_LGKM0();
    __builtin_amdgcn_s_setprio(1);
#pragma unroll
    for (int m = 0; m < 8; ++m)
#pragma unroll
      for (int n = 0; n < NACC; ++n)
        accC[m][n] = __builtin_amdgcn_mfma_f32_16x16x32_bf16(
            aF[m], bF[n], accC[m][n], 0, 0, 0);
    __builtin_amdgcn_s_setprio(0);
  }
  WAIT_VM(0);                           // drain tail stages (LDS-dest only)

  // ---- epilogue. C/D: col = lane&15, row = (lane>>4)*4 + j
  const int rB0 = wr * 128 + gh * 4;
  const int cB0 = colBase + wc * WN + rl;
#pragma unroll
  for (int m = 0; m < 8; ++m) {
#pragma unroll
    for (int n = 0; n < NACC; ++n) {
#pragma unroll
      for (int j = 0; j < 4; ++j) {
        int r = rB0 + m * 16 + j;
        if (r < rowsValid) {
          size_t idx = (size_t)(rowBase + r) * N_DIM + (cB0 + n * 16);
          float v = accC[m][n][j];
          if (RELU2) {
            float rv = v > 0.f ? v : 0.f;
            float hf = (float)(__bf16)rv;              // bf16(relu(acc))
            ((__bf16*)Cout)[idx] = (__bf16)(hf * hf);  // bf16 square
          } else {
            ((float*)Cout)[idx] = (float)(__bf16)v;    // float(bf16(acc))
          }
        }
      }
    }
  }
}

extern "C" void kernel_launch(void* const* d_in, const int* in_sizes, int n_in,
                              void* d_out, int out_size, void* d_ws, size_t ws_size,
                              hipStream_t stream) {
  const float* x   = (const float*)d_in[0];
  const int*   cnt = (const int*)d_in[1];
  const float* wu  = (const float*)d_in[2];
  const float* wd  = (const float*)d_in[3];
  float* out = (float*)d_out;
  char*  ws  = (char*)d_ws;

  unsigned short* xb   = (unsigned short*)(ws);                // 16 MiB
  unsigned short* hbuf = (unsigned short*)(ws + (16u << 20));  // 32 MiB

  cvt_f32_bf16<<<2048, 256, 0, stream>>>(x, xb, T_TOK * D_DIM / 4);

  // GEMM1: h = bf16(bf16(relu(x@wu^T))^2); BN=256, 3 buffers (144K LDS)
  ggt<D_DIM, H_DIM, 256, 3, true ><<<dim3(40, H_DIM / 256), dim3(512), 0, stream>>>(
      xb, wu, cnt, (void*)hbuf);
  // GEMM2: out = float(bf16(h@wd^T)); BN=128, 4 buffers (128K LDS, depth 3)
  ggt<H_DIM, D_DIM, 128, 4, false><<<dim3(40, D_DIM / 128), dim3(512), 0, stream>>>(
      hbuf, wd, cnt, (void*)out);
}